// Round 7
// baseline (333.717 us; speedup 1.0000x reference)
//
#include <hip/hip_runtime.h>

// ModConv2D — StyleGAN2 modulated conv as implicit GEMM, f16 MFMA.
// B=16, H=W=64, CIN=COUT=256, 3x3 SAME, fp32 I/O.
//
// R11: R10 (A-operand from precomputed padded xmod f16 tensor, no xs LDS)
//      with a ws_size GUARD: R10 needs 36.9 MB workspace; if the harness
//      gives less, fall back to R9's proven path (140 us). R10's double
//      container failure is consistent with an OOB workspace write in
//      xmod_k — this round cannot crash on that, and counters will reveal
//      which path executed (LDS 12.5K + xmod_k dispatch vs 46K).

#define HH 64
#define WW 64
#define CI 256
#define CO 256
#define XP 66            // padded spatial extent (halo -1..64 -> 0..65)
#define CIPITCH 40       // (fallback) ushorts per (row,col): 32 ci + 8 pad
#define XCOLS 66         // (fallback)

typedef float    f32x4 __attribute__((ext_vector_type(4)));
typedef _Float16 f16x8 __attribute__((ext_vector_type(8)));
typedef __fp16   fp16x2 __attribute__((ext_vector_type(2)));

__device__ __forceinline__ unsigned pk2(float a, float b) {
    fp16x2 h = __builtin_amdgcn_cvt_pkrtz(a, b);
    return __builtin_bit_cast(unsigned, h);
}

// ---- fused prep: Wt2 in DMA order AND scale2 partial sums (R9, proven) ----
// Wt2 ushort index: (((c*9 + t9)*4 + fq)*256 + co)*8 + e,  k = t9*256+c*32+fq*8+e
__global__ __launch_bounds__(256) void prep(
    const float* __restrict__ kern,    // [9][CI][CO]
    const float* __restrict__ style,   // [B][CI]
    ushort* __restrict__ Wt2,          // DMA-ordered, 9*256*256 ushorts
    float* __restrict__ scale2)        // [B][CO], pre-zeroed
{
    __shared__ ushort tile[64][65];
    __shared__ float  sqt[64][65];
    __shared__ float  st2l[16][64];

    const int kt = blockIdx.x >> 2;     // 0..35
    const int ct = blockIdx.x & 3;
    const int k0 = kt * 64, c0 = ct * 64;
    const int ci0 = k0 & 255;
    const int tid = threadIdx.x;
    const int r = tid >> 2, q = tid & 3;

    #pragma unroll
    for (int p = 0; p < 4; ++p) {
        const int i = p * 256 + tid;            // 0..1023
        const int bb = i >> 6, rr = i & 63;
        const float s = style[bb * CI + ci0 + rr] + 1.0f;
        st2l[bb][rr] = s * s;
    }

    const float* src = kern + (size_t)(k0 + r) * CO + c0 + q * 16;
    #pragma unroll
    for (int j = 0; j < 16; ++j) {
        const float v = src[j];
        _Float16 h = (_Float16)v;
        tile[q * 16 + j][r] = __builtin_bit_cast(unsigned short, h);
        sqt[r][q * 16 + j] = v * v;             // fp32 squares for demod
    }
    __syncthreads();

    const int co_w = c0 + r;
    #pragma unroll
    for (int j = 0; j < 16; ++j) {
        const int k   = k0 + q * 16 + j;
        const int t9  = k >> 8;
        const int rem = k & 255;
        const int cc  = rem >> 5;
        const int fq  = (rem >> 3) & 3;
        const int e   = k & 7;
        Wt2[((((size_t)cc * 9 + t9) * 4 + fq) * 256 + co_w) * 8 + e] =
            tile[r][q * 16 + j];
    }

    const int co = tid & 63;
    const int bq = tid >> 6;                    // wave-uniform
    float acc[4] = {0.f, 0.f, 0.f, 0.f};
    #pragma unroll 4
    for (int rr = 0; rr < 64; ++rr) {
        const float s = sqt[rr][co];
        #pragma unroll
        for (int bb = 0; bb < 4; ++bb)
            acc[bb] += s * st2l[bq * 4 + bb][rr];   // broadcast read
    }
    #pragma unroll
    for (int bb = 0; bb < 4; ++bb)
        atomicAdd(&scale2[(bq * 4 + bb) * CO + c0 + co], acc[bb]);
}

// ---- xmod: padded modulated-x f16 tensor (R10 path only) ----
__global__ __launch_bounds__(256) void xmod_k(
    const float* __restrict__ x,        // [B][64][64][CI]
    const float* __restrict__ style,    // [B][CI]
    ushort* __restrict__ Xm)            // [B][66][66][CI]
{
    const int b  = blockIdx.x / XP;
    const int hh = blockIdx.x - b * XP;
    const int tid = threadIdx.x;
    ushort* dst = Xm + ((size_t)(b * XP + hh)) * XP * CI;

    if (hh == 0 || hh == XP - 1) {
        const uint4 z = {0, 0, 0, 0};
        #pragma unroll
        for (int p = 0; p < 9; ++p) {
            const int t = p * 256 + tid;
            if (t < 2112) *(uint4*)(dst + t * 8) = z;
        }
        return;
    }

    const int l = tid & 63;           // ci group
    const int q = tid >> 6;           // col group
    const int ci0 = l * 4;
    const int rg = hh - 1;

    f32x4 st = *(const f32x4*)(style + b * CI + ci0);
    st.x += 1.f; st.y += 1.f; st.z += 1.f; st.w += 1.f;

    const float* srow = x + ((size_t)(b * HH + rg)) * WW * CI + ci0;
    #pragma unroll
    for (int k = 0; k < 17; ++k) {
        const int cc = q + 4 * k;
        if (cc < XP) {
            uint2 u = {0, 0};
            if (cc >= 1 && cc <= WW) {
                const f32x4 v = *(const f32x4*)(srow + (size_t)(cc - 1) * CI);
                const f32x4 m = v * st;
                u.x = pk2(m.x, m.y);
                u.y = pk2(m.z, m.w);
            }
            *(uint2*)(dst + cc * CI + ci0) = u;
        }
    }
}

// ---- R10 gemm: af from global xmod, bf via DMA'd LDS ----
__global__ __launch_bounds__(256) void gemm_xm(
    const ushort* __restrict__ Xm,      // [B][66][66][CI] f16, modulated+padded
    const ushort* __restrict__ Wt2,     // DMA-ordered f16 weights
    const float* __restrict__ scale2,   // [B][CO] sum-of-squares
    float* __restrict__ y)              // [B][H][W][CO] fp32
{
    __shared__ __align__(16) ushort bs[3 * 4096];   // 3 bufs x 8192 B

    const int tid  = threadIdx.x;
    const int lane = tid & 63;
    const int wave = tid >> 6;

    const int mtile = blockIdx.x >> 1;
    const int n0    = (blockIdx.x & 1) * 128;
    const int p0    = mtile * 128;
    const int b     = p0 >> 12;
    const int h0    = (p0 >> 6) & 63;

    const int wm = (wave & 1) * 64;
    const int wn = (wave >> 1) * 64;
    const int fr = lane & 15;
    const int fq = lane >> 4;

    const ushort* xb = Xm + (size_t)b * XP * XP * CI;
    unsigned offA[4];
    #pragma unroll
    for (int i = 0; i < 4; ++i) {
        const int mb = wm + i * 16;
        const int R0 = h0 + (mb >> 6);
        const int C0 = (mb & 63) + fr;
        offA[i] = (unsigned)((R0 * XP + C0) * CI + fq * 8);
    }

    auto issue_tile = [&](int cn, int t9n, int bufn) {
        const ushort* gb = Wt2 + ((size_t)((cn * 9 + t9n) * 4) * 256 + n0) * 8;
        #pragma unroll
        for (int p = 0; p < 2; ++p) {
            const int task = p * 256 + tid;
            const ushort* g = gb + (size_t)(((task >> 7) << 8) + (task & 127)) * 8;
            const ushort* l = bs + bufn * 4096 + (p * 256 + (tid & ~63)) * 8;
            __builtin_amdgcn_global_load_lds(
                (const __attribute__((address_space(1))) void*)g,
                (__attribute__((address_space(3))) void*)l,
                16, 0, 0);
        }
    };

    f32x4 acc[4][4] = {};

    issue_tile(0, 0, 0);
    issue_tile(0, 1, 1);

    for (int c = 0; c < 8; ++c) {
        #pragma unroll
        for (int t9 = 0; t9 < 9; ++t9) {
            if (c == 7 && t9 == 8)
                asm volatile("s_waitcnt vmcnt(0) lgkmcnt(0)" ::: "memory");
            else
                asm volatile("s_waitcnt vmcnt(2) lgkmcnt(0)" ::: "memory");
            __builtin_amdgcn_s_barrier();

            {
                const int t2 = (t9 + 2 >= 9) ? t9 + 2 - 9 : t9 + 2;
                const int c2 = (t9 >= 7) ? c + 1 : c;
                if (c2 < 8) issue_tile(c2, t2, (t9 + 2) % 3);
            }

            const int dh = t9 / 3;
            const int dw = t9 - dh * 3;
            const int buf = t9 % 3;

            f16x8 af[4], bf[4];
            #pragma unroll
            for (int i = 0; i < 4; ++i)
                af[i] = *(const f16x8*)(xb + offA[i] + (dh * XP + dw) * CI);
            #pragma unroll
            for (int j = 0; j < 4; ++j)
                bf[j] = *(const f16x8*)(bs + buf * 4096 + fq * 1024
                                        + (wn + j * 16 + fr) * 8);
            #pragma unroll
            for (int i = 0; i < 4; ++i)
                #pragma unroll
                for (int j = 0; j < 4; ++j)
                    acc[i][j] = __builtin_amdgcn_mfma_f32_16x16x32_f16(
                        af[i], bf[j], acc[i][j], 0, 0, 0);
        }
        #pragma unroll
        for (int i = 0; i < 4; ++i) offA[i] += 32;
    }

    float sc[4];
    #pragma unroll
    for (int j = 0; j < 4; ++j)
        sc[j] = __frsqrt_rn(scale2[b * CO + n0 + wn + j * 16 + fr] + 1e-8f);
    #pragma unroll
    for (int i = 0; i < 4; ++i) {
        const int m_base = p0 + wm + i * 16 + fq * 4;
        #pragma unroll
        for (int j = 0; j < 4; ++j) {
            float* yp = y + (size_t)m_base * CO + n0 + wn + j * 16 + fr;
            #pragma unroll
            for (int r = 0; r < 4; ++r)
                yp[(size_t)r * CO] = acc[i][j][r] * sc[j];
        }
    }
}

// ---- R9 gemm fallback (proven 140 us): xs staged in LDS per slice ----
__global__ __launch_bounds__(256) void gemm_lds(
    const float* __restrict__ x,        // [B][H][W][CI] fp32
    const ushort* __restrict__ Wt2,     // DMA-ordered f16 weights
    const float* __restrict__ style,    // [B][CI]
    const float* __restrict__ scale2,   // [B][CO]
    float* __restrict__ y)              // [B][H][W][CO] fp32
{
    __shared__ __align__(16) ushort xs[4 * XCOLS * CIPITCH];  // 21120 B
    __shared__ __align__(16) ushort bs[3 * 4096];             // 24576 B
    __shared__ float s_style[CI];

    const int tid  = threadIdx.x;
    const int lane = tid & 63;
    const int wave = tid >> 6;

    const int mtile = blockIdx.x >> 1;
    const int n0    = (blockIdx.x & 1) * 128;
    const int p0    = mtile * 128;
    const int b     = p0 >> 12;
    const int h0    = (p0 >> 6) & 63;

    s_style[tid] = style[b * CI + tid] + 1.0f;

    const int wm = (wave & 1) * 64;
    const int wn = (wave >> 1) * 64;
    const int fr = lane & 15;
    const int fq = lane >> 4;
    const int xlane = fr * CIPITCH + fq * 8;

    auto issue_tile = [&](int cn, int t9n, int bufn) {
        const ushort* gb = Wt2 + ((size_t)((cn * 9 + t9n) * 4) * 256 + n0) * 8;
        #pragma unroll
        for (int p = 0; p < 2; ++p) {
            const int task = p * 256 + tid;
            const ushort* g = gb + (size_t)(((task >> 7) << 8) + (task & 127)) * 8;
            const ushort* l = bs + bufn * 4096 + (p * 256 + (tid & ~63)) * 8;
            __builtin_amdgcn_global_load_lds(
                (const __attribute__((address_space(1))) void*)g,
                (__attribute__((address_space(3))) void*)l,
                16, 0, 0);
        }
    };

    f32x4 acc[4][4] = {};

    issue_tile(0, 0, 0);
    issue_tile(0, 1, 1);

    for (int c = 0; c < 8; ++c) {
        #pragma unroll
        for (int t9 = 0; t9 < 9; ++t9) {
            asm volatile("s_waitcnt vmcnt(2) lgkmcnt(0)" ::: "memory");
            __builtin_amdgcn_s_barrier();

            if (t9 == 0) {
                #pragma unroll
                for (int p = 0; p < 9; ++p) {
                    const int task = p * 256 + tid;
                    if (task < 2112) {
                        const int rowcol = task >> 3;
                        const int chunk  = task & 7;
                        const int row = rowcol / XCOLS;
                        const int col = rowcol - row * XCOLS;
                        const int rg = h0 - 1 + row;
                        const int cg = col - 1;
                        f32x4 v = {0.f, 0.f, 0.f, 0.f};
                        if ((unsigned)rg < 64u && (unsigned)cg < 64u)
                            v = *(const f32x4*)(x + ((size_t)((b * HH + rg) * WW + cg)) * CI
                                                  + c * 32 + chunk * 4);
                        const f32x4 st = *(const f32x4*)(s_style + c * 32 + chunk * 4);
                        const f32x4 m = v * st;
                        uint2 u;
                        u.x = pk2(m.x, m.y);
                        u.y = pk2(m.z, m.w);
                        *(uint2*)(xs + rowcol * CIPITCH + chunk * 4) = u;
                    }
                }
                asm volatile("s_waitcnt lgkmcnt(0)" ::: "memory");
                __builtin_amdgcn_s_barrier();
            }

            {
                const int t2 = (t9 + 2 >= 9) ? t9 + 2 - 9 : t9 + 2;
                const int c2 = (t9 >= 7) ? c + 1 : c;
                if (c2 < 8) issue_tile(c2, t2, (t9 + 2) % 3);
            }

            const int buf = t9 % 3;
            const int dh  = t9 / 3;
            const int dw  = t9 - dh * 3;

            f16x8 af[4], bf[4];
            #pragma unroll
            for (int i = 0; i < 4; ++i) {
                const int mb   = wm + i * 16;
                const int mrow = (mb >> 6) + dh;
                const int mcol = (mb & 63) + dw;
                af[i] = *(const f16x8*)(xs + (mrow * XCOLS + mcol) * CIPITCH + xlane);
            }
            #pragma unroll
            for (int j = 0; j < 4; ++j)
                bf[j] = *(const f16x8*)(bs + buf * 4096 + fq * 1024
                                        + (wn + j * 16 + fr) * 8);
            #pragma unroll
            for (int i = 0; i < 4; ++i)
                #pragma unroll
                for (int j = 0; j < 4; ++j)
                    acc[i][j] = __builtin_amdgcn_mfma_f32_16x16x32_f16(
                        af[i], bf[j], acc[i][j], 0, 0, 0);
        }
    }

    float sc[4];
    #pragma unroll
    for (int j = 0; j < 4; ++j)
        sc[j] = __frsqrt_rn(scale2[b * CO + n0 + wn + j * 16 + fr] + 1e-8f);
    #pragma unroll
    for (int i = 0; i < 4; ++i) {
        const int m_base = p0 + wm + i * 16 + fq * 4;
        #pragma unroll
        for (int j = 0; j < 4; ++j) {
            float* yp = y + (size_t)m_base * CO + n0 + wn + j * 16 + fr;
            #pragma unroll
            for (int r = 0; r < 4; ++r)
                yp[(size_t)r * CO] = acc[i][j][r] * sc[j];
        }
    }
}

extern "C" void kernel_launch(void* const* d_in, const int* in_sizes, int n_in,
                              void* d_out, int out_size, void* d_ws, size_t ws_size,
                              hipStream_t stream) {
    const float* x     = (const float*)d_in[0];  // [16,64,64,256]
    const float* style = (const float*)d_in[1];  // [16,256]
    const float* kern  = (const float*)d_in[2];  // [3,3,256,256]
    float* out = (float*)d_out;                  // [16,64,64,256]

    float*  scale2 = (float*)d_ws;                          // 16 KB
    ushort* Wt2    = (ushort*)((char*)d_ws + 16384);        // 1.18 MB

    const size_t xm_off  = 16384 + 1179648;
    const size_t xm_size = (size_t)16 * XP * XP * CI * 2;   // 35.7 MB

    hipMemsetAsync(scale2, 0, 16 * CO * sizeof(float), stream);
    prep<<<144, 256, 0, stream>>>(kern, style, Wt2, scale2);

    if (ws_size >= xm_off + xm_size) {
        ushort* Xm = (ushort*)((char*)d_ws + xm_off);
        xmod_k<<<16 * XP, 256, 0, stream>>>(x, style, Xm);
        gemm_xm<<<512 * 2, 256, 0, stream>>>(Xm, Wt2, scale2, out);
    } else {
        gemm_lds<<<512 * 2, 256, 0, stream>>>(x, Wt2, style, scale2, out);
    }
}

// Round 8
// 248.011 us; speedup vs baseline: 1.3456x; 1.3456x over previous
//
#include <hip/hip_runtime.h>

// ModConv2D — StyleGAN2 modulated conv as implicit GEMM, f16 MFMA.
// B=16, H=W=64, CIN=COUT=256, 3x3 SAME, fp32 I/O.
//
// R12: both MFMA operands from LDS, both staged by global_load_lds DMA.
//   - Xm[b][66][66][256] f16 = x*(style+1), halo baked in (proven R11).
//   - gemm_dma: xs double-buffer (2 x 20KB, 5 wave-uniform DMA issues/slice
//     at t9==4, consumed next slice) + bs triple-buffer (R9 proven). Loop
//     body has ONLY DMA + ds_read + MFMA -> vmcnt queue holds DMA ops only,
//     so counted waits are exact: vmcnt(2) everywhere except vmcnt(7) at
//     t9 in {5,6} while the 5 xs ops are in flight (c<7; wave-uniform branch).
//     R11 lesson: af-from-global put af loads in the vmcnt queue and the
//     per-step vmcnt(2) drained them -> 222us. Never mix counted DMA waits
//     with compiler vmem loads in the loop.
//   - LDS 64KB exactly -> 2 blocks/CU; no VALU modulate, no bounds checks.

#define HH 64
#define WW 64
#define CI 256
#define CO 256
#define XP 66            // padded spatial extent
#define CIPITCH 40       // (fallback kernel only)
#define XCOLS 66

typedef float    f32x4 __attribute__((ext_vector_type(4)));
typedef _Float16 f16x8 __attribute__((ext_vector_type(8)));
typedef __fp16   fp16x2 __attribute__((ext_vector_type(2)));

__device__ __forceinline__ unsigned pk2(float a, float b) {
    fp16x2 h = __builtin_amdgcn_cvt_pkrtz(a, b);
    return __builtin_bit_cast(unsigned, h);
}

// ---- fused prep: Wt2 in DMA order AND scale2 partial sums (proven) ----
// Wt2 ushort index: (((c*9 + t9)*4 + fq)*256 + co)*8 + e,  k = t9*256+c*32+fq*8+e
__global__ __launch_bounds__(256) void prep(
    const float* __restrict__ kern,    // [9][CI][CO]
    const float* __restrict__ style,   // [B][CI]
    ushort* __restrict__ Wt2,          // DMA-ordered, 9*256*256 ushorts
    float* __restrict__ scale2)        // [B][CO], pre-zeroed
{
    __shared__ ushort tile[64][65];
    __shared__ float  sqt[64][65];
    __shared__ float  st2l[16][64];

    const int kt = blockIdx.x >> 2;     // 0..35
    const int ct = blockIdx.x & 3;
    const int k0 = kt * 64, c0 = ct * 64;
    const int ci0 = k0 & 255;
    const int tid = threadIdx.x;
    const int r = tid >> 2, q = tid & 3;

    #pragma unroll
    for (int p = 0; p < 4; ++p) {
        const int i = p * 256 + tid;            // 0..1023
        const int bb = i >> 6, rr = i & 63;
        const float s = style[bb * CI + ci0 + rr] + 1.0f;
        st2l[bb][rr] = s * s;
    }

    const float* src = kern + (size_t)(k0 + r) * CO + c0 + q * 16;
    #pragma unroll
    for (int j = 0; j < 16; ++j) {
        const float v = src[j];
        _Float16 h = (_Float16)v;
        tile[q * 16 + j][r] = __builtin_bit_cast(unsigned short, h);
        sqt[r][q * 16 + j] = v * v;             // fp32 squares for demod
    }
    __syncthreads();

    const int co_w = c0 + r;
    #pragma unroll
    for (int j = 0; j < 16; ++j) {
        const int k   = k0 + q * 16 + j;
        const int t9  = k >> 8;
        const int rem = k & 255;
        const int cc  = rem >> 5;
        const int fq  = (rem >> 3) & 3;
        const int e   = k & 7;
        Wt2[((((size_t)cc * 9 + t9) * 4 + fq) * 256 + co_w) * 8 + e] =
            tile[r][q * 16 + j];
    }

    const int co = tid & 63;
    const int bq = tid >> 6;                    // wave-uniform
    float acc[4] = {0.f, 0.f, 0.f, 0.f};
    #pragma unroll 4
    for (int rr = 0; rr < 64; ++rr) {
        const float s = sqt[rr][co];
        #pragma unroll
        for (int bb = 0; bb < 4; ++bb)
            acc[bb] += s * st2l[bq * 4 + bb][rr];   // broadcast read
    }
    #pragma unroll
    for (int bb = 0; bb < 4; ++bb)
        atomicAdd(&scale2[(bq * 4 + bb) * CO + c0 + co], acc[bb]);
}

// ---- xmod: padded modulated-x f16 tensor (proven R11) ----
__global__ __launch_bounds__(256) void xmod_k(
    const float* __restrict__ x,        // [B][64][64][CI]
    const float* __restrict__ style,    // [B][CI]
    ushort* __restrict__ Xm)            // [B][66][66][CI]
{
    const int b  = blockIdx.x / XP;
    const int hh = blockIdx.x - b * XP;
    const int tid = threadIdx.x;
    ushort* dst = Xm + ((size_t)(b * XP + hh)) * XP * CI;

    if (hh == 0 || hh == XP - 1) {
        const uint4 z = {0, 0, 0, 0};
        #pragma unroll
        for (int p = 0; p < 9; ++p) {
            const int t = p * 256 + tid;
            if (t < 2112) *(uint4*)(dst + t * 8) = z;
        }
        return;
    }

    const int l = tid & 63;           // ci group
    const int q = tid >> 6;           // col group
    const int ci0 = l * 4;
    const int rg = hh - 1;

    f32x4 st = *(const f32x4*)(style + b * CI + ci0);
    st.x += 1.f; st.y += 1.f; st.z += 1.f; st.w += 1.f;

    const float* srow = x + ((size_t)(b * HH + rg)) * WW * CI + ci0;
    #pragma unroll
    for (int k = 0; k < 17; ++k) {
        const int cc = q + 4 * k;
        if (cc < XP) {
            uint2 u = {0, 0};
            if (cc >= 1 && cc <= WW) {
                const f32x4 v = *(const f32x4*)(srow + (size_t)(cc - 1) * CI);
                const f32x4 m = v * st;
                u.x = pk2(m.x, m.y);
                u.y = pk2(m.z, m.w);
            }
            *(uint2*)(dst + cc * CI + ci0) = u;
        }
    }
}

// ---- R12 gemm: xs AND bs staged via global_load_lds DMA ----
// xs layout per buffer: [rowcol 0..263][ci32] f16 (rowcol = row*66+col), linear
// in DMA task order (task = rowcol*4 + chunk, 16B each). Tasks 1056..1279 are
// dummy (5th wave-uniform issue padding); LDS buffer is 1280*16B = 20KB.
__global__ __launch_bounds__(256) void gemm_dma(
    const ushort* __restrict__ Xm,      // [B][66][66][CI] f16, modulated+padded
    const ushort* __restrict__ Wt2,     // DMA-ordered f16 weights
    const float* __restrict__ scale2,   // [B][CO]
    float* __restrict__ y)              // [B][H][W][CO] fp32
{
    __shared__ __align__(16) ushort xs2[2][10240];  // 2 x 20480 B
    __shared__ __align__(16) ushort bs[3 * 4096];   // 3 x 8192 B   (total 64 KB)

    const int tid  = threadIdx.x;
    const int lane = tid & 63;
    const int wave = tid >> 6;

    const int mtile = blockIdx.x >> 1;
    const int n0    = (blockIdx.x & 1) * 128;
    const int p0    = mtile * 128;            // 2 image rows of one sample
    const int b     = p0 >> 12;
    const int h0    = (p0 >> 6) & 63;

    const int wm = (wave & 1) * 64;
    const int wn = (wave >> 1) * 64;
    const int fr = lane & 15;
    const int fq = lane >> 4;

    const ushort* xb = Xm + (size_t)b * XP * XP * CI;

    // per-thread xs DMA source offsets (slice-invariant; +c*32 per slice)
    int xoff5[5];
    #pragma unroll
    for (int p = 0; p < 5; ++p) {
        const int task = p * 256 + tid;       // 0..1279
        const int rc = task >> 2;             // rowcol 0..319 (>=264 dummy)
        const int ch = task & 3;
        xoff5[p] = (rc < 264)
            ? (((h0 + rc / 66) * XP + (rc % 66)) * CI + ch * 8)
            : 0;                               // dummy: read Xm[b] base (valid)
    }

    auto issue_xs = [&](int cn, int bufn) {
        #pragma unroll
        for (int p = 0; p < 5; ++p) {
            const ushort* g = xb + xoff5[p] + cn * 32;
            const ushort* l = &xs2[bufn][(p * 256 + (tid & ~63)) * 8];
            __builtin_amdgcn_global_load_lds(
                (const __attribute__((address_space(1))) void*)g,
                (__attribute__((address_space(3))) void*)l,
                16, 0, 0);
        }
    };

    auto issue_tile = [&](int cn, int t9n, int bufn) {
        const ushort* gb = Wt2 + ((size_t)((cn * 9 + t9n) * 4) * 256 + n0) * 8;
        #pragma unroll
        for (int p = 0; p < 2; ++p) {
            const int task = p * 256 + tid;
            const ushort* g = gb + (size_t)(((task >> 7) << 8) + (task & 127)) * 8;
            const ushort* l = bs + bufn * 4096 + (p * 256 + (tid & ~63)) * 8;
            __builtin_amdgcn_global_load_lds(
                (const __attribute__((address_space(1))) void*)g,
                (__attribute__((address_space(3))) void*)l,
                16, 0, 0);
        }
    };

    f32x4 acc[4][4] = {};

    // prologue: xs slice 0 (5 ops), then bs tiles 0,1 (4 ops)
    issue_xs(0, 0);
    issue_tile(0, 0, 0);
    issue_tile(0, 1, 1);

    for (int c = 0; c < 8; ++c) {
        const int xbuf = c & 1;
        #pragma unroll
        for (int t9 = 0; t9 < 9; ++t9) {
            // FIFO-counted waits (queue = DMA ops only):
            // need: bs tile n retired (+ xs slice c retired when t9==0).
            // younger-than-tile-n = bs(n+1) [2] + xs [5 iff t9 in {5,6}, c<7].
            if ((t9 == 5 || t9 == 6) && c < 7)
                asm volatile("s_waitcnt vmcnt(7) lgkmcnt(0)" ::: "memory");
            else
                asm volatile("s_waitcnt vmcnt(2) lgkmcnt(0)" ::: "memory");
            __builtin_amdgcn_s_barrier();

            // issue bs tile n+2
            {
                const int t2 = (t9 + 2 >= 9) ? t9 - 7 : t9 + 2;
                const int c2 = (t9 >= 7) ? c + 1 : c;
                if (c2 < 8) issue_tile(c2, t2, t2 % 3);
            }
            // issue next slice's xs (lands by the (c+1,0) barrier: vmcnt(2))
            if (t9 == 4 && c < 7) issue_xs(c + 1, xbuf ^ 1);

            const int dh  = t9 / 3;               // 0..2
            const int dw  = t9 - dh * 3;          // 0..2
            const int buf = t9 % 3;

            f16x8 af[4], bf[4];
            #pragma unroll
            for (int i = 0; i < 4; ++i) {
                const int mb = wm + i * 16;
                const int rc = ((mb >> 6) + dh) * XCOLS + (mb & 63) + fr + dw;
                af[i] = *(const f16x8*)(&xs2[xbuf][rc * 32 + fq * 8]);
            }
            #pragma unroll
            for (int j = 0; j < 4; ++j)
                bf[j] = *(const f16x8*)(bs + buf * 4096 + fq * 1024
                                        + (wn + j * 16 + fr) * 8);
            #pragma unroll
            for (int i = 0; i < 4; ++i)
                #pragma unroll
                for (int j = 0; j < 4; ++j)
                    acc[i][j] = __builtin_amdgcn_mfma_f32_16x16x32_f16(
                        af[i], bf[j], acc[i][j], 0, 0, 0);
        }
    }

    // ---- epilogue: demod scale + store. D: col=lane&15, row=(lane>>4)*4+reg ----
    float sc[4];
    #pragma unroll
    for (int j = 0; j < 4; ++j)
        sc[j] = __frsqrt_rn(scale2[b * CO + n0 + wn + j * 16 + fr] + 1e-8f);
    #pragma unroll
    for (int i = 0; i < 4; ++i) {
        const int m_base = p0 + wm + i * 16 + fq * 4;
        #pragma unroll
        for (int j = 0; j < 4; ++j) {
            float* yp = y + (size_t)m_base * CO + n0 + wn + j * 16 + fr;
            #pragma unroll
            for (int r = 0; r < 4; ++r)
                yp[(size_t)r * CO] = acc[i][j][r] * sc[j];
        }
    }
}

// ---- fallback (ws too small): R9 proven 140us path ----
__global__ __launch_bounds__(256) void gemm_lds(
    const float* __restrict__ x,
    const ushort* __restrict__ Wt2,
    const float* __restrict__ style,
    const float* __restrict__ scale2,
    float* __restrict__ y)
{
    __shared__ __align__(16) ushort xs[4 * XCOLS * CIPITCH];
    __shared__ __align__(16) ushort bs[3 * 4096];
    __shared__ float s_style[CI];

    const int tid  = threadIdx.x;
    const int lane = tid & 63;
    const int wave = tid >> 6;

    const int mtile = blockIdx.x >> 1;
    const int n0    = (blockIdx.x & 1) * 128;
    const int p0    = mtile * 128;
    const int b     = p0 >> 12;
    const int h0    = (p0 >> 6) & 63;

    s_style[tid] = style[b * CI + tid] + 1.0f;

    const int wm = (wave & 1) * 64;
    const int wn = (wave >> 1) * 64;
    const int fr = lane & 15;
    const int fq = lane >> 4;
    const int xlane = fr * CIPITCH + fq * 8;

    auto issue_tile = [&](int cn, int t9n, int bufn) {
        const ushort* gb = Wt2 + ((size_t)((cn * 9 + t9n) * 4) * 256 + n0) * 8;
        #pragma unroll
        for (int p = 0; p < 2; ++p) {
            const int task = p * 256 + tid;
            const ushort* g = gb + (size_t)(((task >> 7) << 8) + (task & 127)) * 8;
            const ushort* l = bs + bufn * 4096 + (p * 256 + (tid & ~63)) * 8;
            __builtin_amdgcn_global_load_lds(
                (const __attribute__((address_space(1))) void*)g,
                (__attribute__((address_space(3))) void*)l,
                16, 0, 0);
        }
    };

    f32x4 acc[4][4] = {};

    issue_tile(0, 0, 0);
    issue_tile(0, 1, 1);

    for (int c = 0; c < 8; ++c) {
        #pragma unroll
        for (int t9 = 0; t9 < 9; ++t9) {
            asm volatile("s_waitcnt vmcnt(2) lgkmcnt(0)" ::: "memory");
            __builtin_amdgcn_s_barrier();

            if (t9 == 0) {
                #pragma unroll
                for (int p = 0; p < 9; ++p) {
                    const int task = p * 256 + tid;
                    if (task < 2112) {
                        const int rowcol = task >> 3;
                        const int chunk  = task & 7;
                        const int row = rowcol / XCOLS;
                        const int col = rowcol - row * XCOLS;
                        const int rg = h0 - 1 + row;
                        const int cg = col - 1;
                        f32x4 v = {0.f, 0.f, 0.f, 0.f};
                        if ((unsigned)rg < 64u && (unsigned)cg < 64u)
                            v = *(const f32x4*)(x + ((size_t)((b * HH + rg) * WW + cg)) * CI
                                                  + c * 32 + chunk * 4);
                        const f32x4 st = *(const f32x4*)(s_style + c * 32 + chunk * 4);
                        const f32x4 m = v * st;
                        uint2 u;
                        u.x = pk2(m.x, m.y);
                        u.y = pk2(m.z, m.w);
                        *(uint2*)(xs + rowcol * CIPITCH + chunk * 4) = u;
                    }
                }
                asm volatile("s_waitcnt lgkmcnt(0)" ::: "memory");
                __builtin_amdgcn_s_barrier();
            }

            {
                const int t2 = (t9 + 2 >= 9) ? t9 - 7 : t9 + 2;
                const int c2 = (t9 >= 7) ? c + 1 : c;
                if (c2 < 8) issue_tile(c2, t2, t2 % 3);
            }

            const int buf = t9 % 3;
            const int dh  = t9 / 3;
            const int dw  = t9 - dh * 3;

            f16x8 af[4], bf[4];
            #pragma unroll
            for (int i = 0; i < 4; ++i) {
                const int mb   = wm + i * 16;
                const int mrow = (mb >> 6) + dh;
                const int mcol = (mb & 63) + dw;
                af[i] = *(const f16x8*)(xs + (mrow * XCOLS + mcol) * CIPITCH + xlane);
            }
            #pragma unroll
            for (int j = 0; j < 4; ++j)
                bf[j] = *(const f16x8*)(bs + buf * 4096 + fq * 1024
                                        + (wn + j * 16 + fr) * 8);
            #pragma unroll
            for (int i = 0; i < 4; ++i)
                #pragma unroll
                for (int j = 0; j < 4; ++j)
                    acc[i][j] = __builtin_amdgcn_mfma_f32_16x16x32_f16(
                        af[i], bf[j], acc[i][j], 0, 0, 0);
        }
    }

    float sc[4];
    #pragma unroll
    for (int j = 0; j < 4; ++j)
        sc[j] = __frsqrt_rn(scale2[b * CO + n0 + wn + j * 16 + fr] + 1e-8f);
    #pragma unroll
    for (int i = 0; i < 4; ++i) {
        const int m_base = p0 + wm + i * 16 + fq * 4;
        #pragma unroll
        for (int j = 0; j < 4; ++j) {
            float* yp = y + (size_t)m_base * CO + n0 + wn + j * 16 + fr;
            #pragma unroll
            for (int r = 0; r < 4; ++r)
                yp[(size_t)r * CO] = acc[i][j][r] * sc[j];
        }
    }
}

extern "C" void kernel_launch(void* const* d_in, const int* in_sizes, int n_in,
                              void* d_out, int out_size, void* d_ws, size_t ws_size,
                              hipStream_t stream) {
    const float* x     = (const float*)d_in[0];  // [16,64,64,256]
    const float* style = (const float*)d_in[1];  // [16,256]
    const float* kern  = (const float*)d_in[2];  // [3,3,256,256]
    float* out = (float*)d_out;                  // [16,64,64,256]

    float*  scale2 = (float*)d_ws;                          // 16 KB
    ushort* Wt2    = (ushort*)((char*)d_ws + 16384);        // 1.18 MB

    const size_t xm_off  = 16384 + 1179648;
    const size_t xm_size = (size_t)16 * XP * XP * CI * 2;   // 35.7 MB

    hipMemsetAsync(scale2, 0, 16 * CO * sizeof(float), stream);
    prep<<<144, 256, 0, stream>>>(kern, style, Wt2, scale2);

    if (ws_size >= xm_off + xm_size) {
        ushort* Xm = (ushort*)((char*)d_ws + xm_off);
        xmod_k<<<16 * XP, 256, 0, stream>>>(x, style, Xm);
        gemm_dma<<<512 * 2, 256, 0, stream>>>(Xm, Wt2, scale2, out);
    } else {
        gemm_lds<<<512 * 2, 256, 0, stream>>>(x, Wt2, style, scale2, out);
    }
}

// Round 9
// 209.034 us; speedup vs baseline: 1.5965x; 1.1865x over previous
//
#include <hip/hip_runtime.h>

// ModConv2D — StyleGAN2 modulated conv as implicit GEMM, f16 MFMA.
// B=16, H=W=64, CIN=COUT=256, 3x3 SAME, fp32 I/O.
//
// R13: occupancy + conflict round (from R12's 136us, MfmaUtil 22.6, 2 blk/CU).
//   - xs SINGLE buffer (20KB): xs(c+1) DMA issued inside step (c,8) after a
//     read-drain mini-barrier; issue order (xs then bs-tile) keeps every
//     step at counted vmcnt(2) (FIFO-verified across slice boundary).
//   - LDS 45056B (xs 20480 + bs 24576) -> 3 blocks/CU, 12 waves.
//   - __launch_bounds__(256,3): loop live state is lean now (no cross-barrier
//     arrays); target ~105 VGPR + 64 acc <= 170. WRITE_SIZE = spill canary.
//   - af bank fix: slot (rc,ch) holds global chunk ch^((rc>>1)&3) (pre-swizzled
//     DMA source), reader uses fq^((rc>>1)&3) -> quarter-wave banks = rc&7
//     spread, 2-way (free). bf already 2-way free.
//   - s_setprio(1) around MFMA cluster (3 async blocks/CU arbitrate).

#define HH 64
#define WW 64
#define CI 256
#define CO 256
#define XP 66            // padded spatial extent
#define CIPITCH 40       // (fallback kernel only)
#define XCOLS 66

typedef float    f32x4 __attribute__((ext_vector_type(4)));
typedef _Float16 f16x8 __attribute__((ext_vector_type(8)));
typedef __fp16   fp16x2 __attribute__((ext_vector_type(2)));

__device__ __forceinline__ unsigned pk2(float a, float b) {
    fp16x2 h = __builtin_amdgcn_cvt_pkrtz(a, b);
    return __builtin_bit_cast(unsigned, h);
}

// ---- fused prep: Wt2 in DMA order AND scale2 partial sums (proven) ----
// Wt2 ushort index: (((c*9 + t9)*4 + fq)*256 + co)*8 + e,  k = t9*256+c*32+fq*8+e
__global__ __launch_bounds__(256) void prep(
    const float* __restrict__ kern,    // [9][CI][CO]
    const float* __restrict__ style,   // [B][CI]
    ushort* __restrict__ Wt2,          // DMA-ordered, 9*256*256 ushorts
    float* __restrict__ scale2)        // [B][CO], pre-zeroed
{
    __shared__ ushort tile[64][65];
    __shared__ float  sqt[64][65];
    __shared__ float  st2l[16][64];

    const int kt = blockIdx.x >> 2;     // 0..35
    const int ct = blockIdx.x & 3;
    const int k0 = kt * 64, c0 = ct * 64;
    const int ci0 = k0 & 255;
    const int tid = threadIdx.x;
    const int r = tid >> 2, q = tid & 3;

    #pragma unroll
    for (int p = 0; p < 4; ++p) {
        const int i = p * 256 + tid;            // 0..1023
        const int bb = i >> 6, rr = i & 63;
        const float s = style[bb * CI + ci0 + rr] + 1.0f;
        st2l[bb][rr] = s * s;
    }

    const float* src = kern + (size_t)(k0 + r) * CO + c0 + q * 16;
    #pragma unroll
    for (int j = 0; j < 16; ++j) {
        const float v = src[j];
        _Float16 h = (_Float16)v;
        tile[q * 16 + j][r] = __builtin_bit_cast(unsigned short, h);
        sqt[r][q * 16 + j] = v * v;             // fp32 squares for demod
    }
    __syncthreads();

    const int co_w = c0 + r;
    #pragma unroll
    for (int j = 0; j < 16; ++j) {
        const int k   = k0 + q * 16 + j;
        const int t9  = k >> 8;
        const int rem = k & 255;
        const int cc  = rem >> 5;
        const int fq  = (rem >> 3) & 3;
        const int e   = k & 7;
        Wt2[((((size_t)cc * 9 + t9) * 4 + fq) * 256 + co_w) * 8 + e] =
            tile[r][q * 16 + j];
    }

    const int co = tid & 63;
    const int bq = tid >> 6;                    // wave-uniform
    float acc[4] = {0.f, 0.f, 0.f, 0.f};
    #pragma unroll 4
    for (int rr = 0; rr < 64; ++rr) {
        const float s = sqt[rr][co];
        #pragma unroll
        for (int bb = 0; bb < 4; ++bb)
            acc[bb] += s * st2l[bq * 4 + bb][rr];   // broadcast read
    }
    #pragma unroll
    for (int bb = 0; bb < 4; ++bb)
        atomicAdd(&scale2[(bq * 4 + bb) * CO + c0 + co], acc[bb]);
}

// ---- xmod: padded modulated-x f16 tensor (proven) ----
__global__ __launch_bounds__(256) void xmod_k(
    const float* __restrict__ x,        // [B][64][64][CI]
    const float* __restrict__ style,    // [B][CI]
    ushort* __restrict__ Xm)            // [B][66][66][CI]
{
    const int b  = blockIdx.x / XP;
    const int hh = blockIdx.x - b * XP;
    const int tid = threadIdx.x;
    ushort* dst = Xm + ((size_t)(b * XP + hh)) * XP * CI;

    if (hh == 0 || hh == XP - 1) {
        const uint4 z = {0, 0, 0, 0};
        #pragma unroll
        for (int p = 0; p < 9; ++p) {
            const int t = p * 256 + tid;
            if (t < 2112) *(uint4*)(dst + t * 8) = z;
        }
        return;
    }

    const int l = tid & 63;           // ci group
    const int q = tid >> 6;           // col group
    const int ci0 = l * 4;
    const int rg = hh - 1;

    f32x4 st = *(const f32x4*)(style + b * CI + ci0);
    st.x += 1.f; st.y += 1.f; st.z += 1.f; st.w += 1.f;

    const float* srow = x + ((size_t)(b * HH + rg)) * WW * CI + ci0;
    #pragma unroll
    for (int k = 0; k < 17; ++k) {
        const int cc = q + 4 * k;
        if (cc < XP) {
            uint2 u = {0, 0};
            if (cc >= 1 && cc <= WW) {
                const f32x4 v = *(const f32x4*)(srow + (size_t)(cc - 1) * CI);
                const f32x4 m = v * st;
                u.x = pk2(m.x, m.y);
                u.y = pk2(m.z, m.w);
            }
            *(uint2*)(dst + cc * CI + ci0) = u;
        }
    }
}

// ---- R13 gemm: single xs (swizzled) + triple bs, all DMA, 3 blocks/CU ----
// xs slot (rc, ch) holds Xm chunk ch ^ ((rc>>1)&3) of the current ci-slice.
__global__ __launch_bounds__(256, 3) void gemm_dma(
    const ushort* __restrict__ Xm,      // [B][66][66][CI] f16, modulated+padded
    const ushort* __restrict__ Wt2,     // DMA-ordered f16 weights
    const float* __restrict__ scale2,   // [B][CO]
    float* __restrict__ y)              // [B][H][W][CO] fp32
{
    __shared__ __align__(16) ushort xs[10240];      // 20480 B (1280 slots x 16B)
    __shared__ __align__(16) ushort bs[3 * 4096];   // 24576 B   (total 45056 B)

    const int tid  = threadIdx.x;
    const int lane = tid & 63;
    const int wave = tid >> 6;

    const int mtile = blockIdx.x >> 1;
    const int n0    = (blockIdx.x & 1) * 128;
    const int p0    = mtile * 128;            // 2 image rows of one sample
    const int b     = p0 >> 12;
    const int h0    = (p0 >> 6) & 63;

    const int wm = (wave & 1) * 64;
    const int wn = (wave >> 1) * 64;
    const int fr = lane & 15;
    const int fq = lane >> 4;

    const ushort* xb = Xm + (size_t)b * XP * XP * CI;

    // xs staging: 5 wave-uniform issues, slot task = p*256+tid, 16B each.
    // Source chunk pre-swizzled: ch' = ch ^ ((rc>>1)&3). Tasks with rc>=264
    // are pad (read Xm[b] base, land in slots 1056..1279).
    auto issue_xs = [&](int cn) {
        #pragma unroll
        for (int p = 0; p < 5; ++p) {
            const int task = p * 256 + tid;       // 0..1279
            const int rc = task >> 2;
            const int ch = (task & 3) ^ ((rc >> 1) & 3);
            const int off = (rc < 264)
                ? (((h0 + rc / 66) * XP + (rc % 66)) * CI + ch * 8 + cn * 32)
                : 0;
            const ushort* g = xb + off;
            const ushort* l = xs + (p * 256 + (tid & ~63)) * 8;
            __builtin_amdgcn_global_load_lds(
                (const __attribute__((address_space(1))) void*)g,
                (__attribute__((address_space(3))) void*)l,
                16, 0, 0);
        }
    };

    auto issue_tile = [&](int cn, int t9n, int bufn) {
        const ushort* gb = Wt2 + ((size_t)((cn * 9 + t9n) * 4) * 256 + n0) * 8;
        #pragma unroll
        for (int p = 0; p < 2; ++p) {
            const int task = p * 256 + tid;
            const ushort* g = gb + (size_t)(((task >> 7) << 8) + (task & 127)) * 8;
            const ushort* l = bs + bufn * 4096 + (p * 256 + (tid & ~63)) * 8;
            __builtin_amdgcn_global_load_lds(
                (const __attribute__((address_space(1))) void*)g,
                (__attribute__((address_space(3))) void*)l,
                16, 0, 0);
        }
    };

    f32x4 acc[4][4] = {};

    // prologue: xs slice 0, bs tiles 0,1.
    // Queue at (0,0) wait: [xs0(5), bs0(2), bs1(2)] -> vmcnt(2) retires xs0+bs0.
    issue_xs(0);
    issue_tile(0, 0, 0);
    issue_tile(0, 1, 1);

    for (int c = 0; c < 8; ++c) {
        #pragma unroll
        for (int t9 = 0; t9 < 9; ++t9) {
            // Steady-state queue at step top: [bs(n)2, (xs(c)5 iff t9==0), bs(n+1)2]
            // with xs issued BEFORE bs(n+1) at (c-1,8) -> vmcnt(2) always
            // retires everything this step needs. Last step drains.
            if (c == 7 && t9 == 8)
                asm volatile("s_waitcnt vmcnt(0) lgkmcnt(0)" ::: "memory");
            else
                asm volatile("s_waitcnt vmcnt(2) lgkmcnt(0)" ::: "memory");
            __builtin_amdgcn_s_barrier();

            const int dh  = t9 / 3;               // 0..2
            const int dw  = t9 - dh * 3;          // 0..2
            const int buf = t9 % 3;

            if (t9 < 8) {
                // issue bs tile n+2 (buf (t9+2)%3; its readers drained above)
                const int t2 = (t9 + 2 >= 9) ? t9 - 7 : t9 + 2;
                const int c2 = (t9 >= 7) ? c + 1 : c;
                if (c2 < 8) issue_tile(c2, t2, t2 % 3);

                f16x8 af[4], bf[4];
                #pragma unroll
                for (int i = 0; i < 4; ++i) {
                    const int mb = wm + i * 16;
                    const int rc = ((mb >> 6) + dh) * XCOLS + (mb & 63) + fr + dw;
                    af[i] = *(const f16x8*)(xs + rc * 32 + ((fq ^ ((rc >> 1) & 3)) * 8));
                }
                #pragma unroll
                for (int j = 0; j < 4; ++j)
                    bf[j] = *(const f16x8*)(bs + buf * 4096 + fq * 1024
                                            + (wn + j * 16 + fr) * 8);
                __builtin_amdgcn_s_setprio(1);
                #pragma unroll
                for (int i = 0; i < 4; ++i)
                    #pragma unroll
                    for (int j = 0; j < 4; ++j)
                        acc[i][j] = __builtin_amdgcn_mfma_f32_16x16x32_f16(
                            af[i], bf[j], acc[i][j], 0, 0, 0);
                __builtin_amdgcn_s_setprio(0);
            } else {
                // t9 == 8: read xs (last readers of slice c), then drain reads
                // + barrier, THEN overwrite xs via DMA for slice c+1.
                f16x8 af[4], bf[4];
                #pragma unroll
                for (int i = 0; i < 4; ++i) {
                    const int mb = wm + i * 16;
                    const int rc = ((mb >> 6) + dh) * XCOLS + (mb & 63) + fr + dw;
                    af[i] = *(const f16x8*)(xs + rc * 32 + ((fq ^ ((rc >> 1) & 3)) * 8));
                }
                #pragma unroll
                for (int j = 0; j < 4; ++j)
                    bf[j] = *(const f16x8*)(bs + buf * 4096 + fq * 1024
                                            + (wn + j * 16 + fr) * 8);
                if (c < 7) {
                    asm volatile("s_waitcnt lgkmcnt(0)" ::: "memory");
                    __builtin_amdgcn_s_barrier();   // all waves' xs reads done
                    issue_xs(c + 1);                // xs first (enables vmcnt(2)
                    issue_tile(c + 1, 1, 1);        //  at next t9==0), then bs
                }
                __builtin_amdgcn_s_setprio(1);
                #pragma unroll
                for (int i = 0; i < 4; ++i)
                    #pragma unroll
                    for (int j = 0; j < 4; ++j)
                        acc[i][j] = __builtin_amdgcn_mfma_f32_16x16x32_f16(
                            af[i], bf[j], acc[i][j], 0, 0, 0);
                __builtin_amdgcn_s_setprio(0);
            }
        }
    }

    // ---- epilogue: demod scale + store. D: col=lane&15, row=(lane>>4)*4+reg ----
    float sc[4];
    #pragma unroll
    for (int j = 0; j < 4; ++j)
        sc[j] = __frsqrt_rn(scale2[b * CO + n0 + wn + j * 16 + fr] + 1e-8f);
    #pragma unroll
    for (int i = 0; i < 4; ++i) {
        const int m_base = p0 + wm + i * 16 + fq * 4;
        #pragma unroll
        for (int j = 0; j < 4; ++j) {
            float* yp = y + (size_t)m_base * CO + n0 + wn + j * 16 + fr;
            #pragma unroll
            for (int r = 0; r < 4; ++r)
                yp[(size_t)r * CO] = acc[i][j][r] * sc[j];
        }
    }
}

// ---- fallback (ws too small): R9 proven 140us path ----
__global__ __launch_bounds__(256) void gemm_lds(
    const float* __restrict__ x,
    const ushort* __restrict__ Wt2,
    const float* __restrict__ style,
    const float* __restrict__ scale2,
    float* __restrict__ y)
{
    __shared__ __align__(16) ushort xsf[4 * XCOLS * CIPITCH];
    __shared__ __align__(16) ushort bs[3 * 4096];
    __shared__ float s_style[CI];

    const int tid  = threadIdx.x;
    const int lane = tid & 63;
    const int wave = tid >> 6;

    const int mtile = blockIdx.x >> 1;
    const int n0    = (blockIdx.x & 1) * 128;
    const int p0    = mtile * 128;
    const int b     = p0 >> 12;
    const int h0    = (p0 >> 6) & 63;

    s_style[tid] = style[b * CI + tid] + 1.0f;

    const int wm = (wave & 1) * 64;
    const int wn = (wave >> 1) * 64;
    const int fr = lane & 15;
    const int fq = lane >> 4;
    const int xlane = fr * CIPITCH + fq * 8;

    auto issue_tile = [&](int cn, int t9n, int bufn) {
        const ushort* gb = Wt2 + ((size_t)((cn * 9 + t9n) * 4) * 256 + n0) * 8;
        #pragma unroll
        for (int p = 0; p < 2; ++p) {
            const int task = p * 256 + tid;
            const ushort* g = gb + (size_t)(((task >> 7) << 8) + (task & 127)) * 8;
            const ushort* l = bs + bufn * 4096 + (p * 256 + (tid & ~63)) * 8;
            __builtin_amdgcn_global_load_lds(
                (const __attribute__((address_space(1))) void*)g,
                (__attribute__((address_space(3))) void*)l,
                16, 0, 0);
        }
    };

    f32x4 acc[4][4] = {};

    issue_tile(0, 0, 0);
    issue_tile(0, 1, 1);

    for (int c = 0; c < 8; ++c) {
        #pragma unroll
        for (int t9 = 0; t9 < 9; ++t9) {
            asm volatile("s_waitcnt vmcnt(2) lgkmcnt(0)" ::: "memory");
            __builtin_amdgcn_s_barrier();

            if (t9 == 0) {
                #pragma unroll
                for (int p = 0; p < 9; ++p) {
                    const int task = p * 256 + tid;
                    if (task < 2112) {
                        const int rowcol = task >> 3;
                        const int chunk  = task & 7;
                        const int row = rowcol / XCOLS;
                        const int col = rowcol - row * XCOLS;
                        const int rg = h0 - 1 + row;
                        const int cg = col - 1;
                        f32x4 v = {0.f, 0.f, 0.f, 0.f};
                        if ((unsigned)rg < 64u && (unsigned)cg < 64u)
                            v = *(const f32x4*)(x + ((size_t)((b * HH + rg) * WW + cg)) * CI
                                                  + c * 32 + chunk * 4);
                        const f32x4 st = *(const f32x4*)(s_style + c * 32 + chunk * 4);
                        const f32x4 m = v * st;
                        uint2 u;
                        u.x = pk2(m.x, m.y);
                        u.y = pk2(m.z, m.w);
                        *(uint2*)(xsf + rowcol * CIPITCH + chunk * 4) = u;
                    }
                }
                asm volatile("s_waitcnt lgkmcnt(0)" ::: "memory");
                __builtin_amdgcn_s_barrier();
            }

            {
                const int t2 = (t9 + 2 >= 9) ? t9 - 7 : t9 + 2;
                const int c2 = (t9 >= 7) ? c + 1 : c;
                if (c2 < 8) issue_tile(c2, t2, t2 % 3);
            }

            const int buf = t9 % 3;
            const int dh  = t9 / 3;
            const int dw  = t9 - dh * 3;

            f16x8 af[4], bf[4];
            #pragma unroll
            for (int i = 0; i < 4; ++i) {
                const int mb   = wm + i * 16;
                const int mrow = (mb >> 6) + dh;
                const int mcol = (mb & 63) + dw;
                af[i] = *(const f16x8*)(xsf + (mrow * XCOLS + mcol) * CIPITCH + xlane);
            }
            #pragma unroll
            for (int j = 0; j < 4; ++j)
                bf[j] = *(const f16x8*)(bs + buf * 4096 + fq * 1024
                                        + (wn + j * 16 + fr) * 8);
            #pragma unroll
            for (int i = 0; i < 4; ++i)
                #pragma unroll
                for (int j = 0; j < 4; ++j)
                    acc[i][j] = __builtin_amdgcn_mfma_f32_16x16x32_f16(
                        af[i], bf[j], acc[i][j], 0, 0, 0);
        }
    }

    float sc[4];
    #pragma unroll
    for (int j = 0; j < 4; ++j)
        sc[j] = __frsqrt_rn(scale2[b * CO + n0 + wn + j * 16 + fr] + 1e-8f);
    #pragma unroll
    for (int i = 0; i < 4; ++i) {
        const int m_base = p0 + wm + i * 16 + fq * 4;
        #pragma unroll
        for (int j = 0; j < 4; ++j) {
            float* yp = y + (size_t)m_base * CO + n0 + wn + j * 16 + fr;
            #pragma unroll
            for (int r = 0; r < 4; ++r)
                yp[(size_t)r * CO] = acc[i][j][r] * sc[j];
        }
    }
}

extern "C" void kernel_launch(void* const* d_in, const int* in_sizes, int n_in,
                              void* d_out, int out_size, void* d_ws, size_t ws_size,
                              hipStream_t stream) {
    const float* x     = (const float*)d_in[0];  // [16,64,64,256]
    const float* style = (const float*)d_in[1];  // [16,256]
    const float* kern  = (const float*)d_in[2];  // [3,3,256,256]
    float* out = (float*)d_out;                  // [16,64,64,256]

    float*  scale2 = (float*)d_ws;                          // 16 KB
    ushort* Wt2    = (ushort*)((char*)d_ws + 16384);        // 1.18 MB

    const size_t xm_off  = 16384 + 1179648;
    const size_t xm_size = (size_t)16 * XP * XP * CI * 2;   // 35.7 MB

    hipMemsetAsync(scale2, 0, 16 * CO * sizeof(float), stream);
    prep<<<144, 256, 0, stream>>>(kern, style, Wt2, scale2);

    if (ws_size >= xm_off + xm_size) {
        ushort* Xm = (ushort*)((char*)d_ws + xm_off);
        xmod_k<<<16 * XP, 256, 0, stream>>>(x, style, Xm);
        gemm_dma<<<512 * 2, 256, 0, stream>>>(Xm, Wt2, scale2, out);
    } else {
        gemm_lds<<<512 * 2, 256, 0, stream>>>(x, Wt2, style, scale2, out);
    }
}